// Round 1
// baseline (288.604 us; speedup 1.0000x reference)
//
#include <hip/hip_runtime.h>

#define SAMPLES_PER_BLOCK 128
#define THREADS 128

__device__ __forceinline__ float fast_sigmoid(float v) {
    // sigmoid(v) = 1 / (1 + exp(-v)); v_exp + v_rcp, ~1 ulp each
    float e = __expf(-v);
    return __builtin_amdgcn_rcpf(1.0f + e);
}

__global__ __launch_bounds__(THREADS) void olcnn_kernel(
    const float* __restrict__ x,
    const float* __restrict__ Wc, const float* __restrict__ bc,
    const float* __restrict__ Wh, const float* __restrict__ bh,
    const float* __restrict__ Wm, const float* __restrict__ bm,
    const float* __restrict__ Wo, const float* __restrict__ bo,
    float* __restrict__ out)
{
    // 128 samples * 81 floats = 41472 B LDS; stride 81 (odd) => 2-way bank
    // aliasing only (free on gfx950, m136).
    __shared__ float sx[SAMPLES_PER_BLOCK * 81];
    const int tid = threadIdx.x;
    const long long blockBase = (long long)blockIdx.x * (SAMPLES_PER_BLOCK * 81);

    // Cooperative coalesced staging: 128*81/4 = 2592 float4 = 20*128 + 32.
    const float4* xv = (const float4*)(x + blockBase);
    float4* sv = (float4*)sx;
    #pragma unroll
    for (int i = 0; i < 20; ++i)
        sv[tid + i * THREADS] = xv[tid + i * THREADS];
    if (tid < 32)
        sv[tid + 20 * THREADS] = xv[tid + 20 * THREADS];
    __syncthreads();

    const float* px = &sx[tid * 81];

    // Patch g=(gr,gc): pixel (pr,pc) lives at x offset gr*27 + pr*9 + gc*3 + pc.
    // hidden group g consumes conv patch g; middle group G consumes hidden of
    // patches 3G..3G+2 -> fully fused, no feat/h materialization beyond regs.
    float m_out[12];
    #pragma unroll
    for (int G = 0; G < 3; ++G) {
        float hbuf[9];
        #pragma unroll
        for (int j = 0; j < 3; ++j) {
            const int g = G * 3 + j;
            const int gr = g / 3, gc = g % 3;
            float pix[9];
            #pragma unroll
            for (int pr = 0; pr < 3; ++pr)
                #pragma unroll
                for (int pc = 0; pc < 3; ++pc)
                    pix[pr * 3 + pc] = px[gr * 27 + pr * 9 + gc * 3 + pc];

            float feat[9];
            #pragma unroll
            for (int k = 0; k < 9; ++k) {
                float acc = bc[g * 9 + k];
                #pragma unroll
                for (int p = 0; p < 9; ++p)
                    acc = fmaf(pix[p], Wc[(g * 9 + k) * 9 + p], acc);
                feat[k] = fast_sigmoid(acc);
            }
            #pragma unroll
            for (int n = 0; n < 3; ++n) {
                float acc = bh[g * 3 + n];
                #pragma unroll
                for (int p = 0; p < 9; ++p)
                    acc = fmaf(feat[p], Wh[(g * 3 + n) * 9 + p], acc);
                hbuf[j * 3 + n] = fast_sigmoid(acc);
            }
        }
        #pragma unroll
        for (int n = 0; n < 4; ++n) {
            float acc = bm[G * 4 + n];
            #pragma unroll
            for (int p = 0; p < 9; ++p)
                acc = fmaf(hbuf[p], Wm[(G * 4 + n) * 9 + p], acc);
            m_out[G * 4 + n] = fast_sigmoid(acc);
        }
    }

    float res[4];
    #pragma unroll
    for (int c = 0; c < 4; ++c) {
        const int grp = c % 3;   // [0,1,2,0]
        float acc = bo[c];
        #pragma unroll
        for (int p = 0; p < 4; ++p)
            acc = fmaf(m_out[grp * 4 + p], Wo[c * 4 + p], acc);
        res[c] = acc;
    }

    float4 o;
    o.x = res[0]; o.y = res[1]; o.z = res[2]; o.w = res[3];
    const long long sample = (long long)blockIdx.x * SAMPLES_PER_BLOCK + tid;
    ((float4*)out)[sample] = o;  // coalesced 16B/lane store
}

extern "C" void kernel_launch(void* const* d_in, const int* in_sizes, int n_in,
                              void* d_out, int out_size, void* d_ws, size_t ws_size,
                              hipStream_t stream) {
    const float* x  = (const float*)d_in[0];
    const float* Wc = (const float*)d_in[1];
    const float* bc = (const float*)d_in[2];
    const float* Wh = (const float*)d_in[3];
    const float* bh = (const float*)d_in[4];
    const float* Wm = (const float*)d_in[5];
    const float* bm = (const float*)d_in[6];
    const float* Wo = (const float*)d_in[7];
    const float* bo = (const float*)d_in[8];
    float* out = (float*)d_out;

    const int B = in_sizes[0] / 81;                  // 524288
    const int blocks = B / SAMPLES_PER_BLOCK;        // 4096 (exact)
    olcnn_kernel<<<blocks, THREADS, 0, stream>>>(x, Wc, bc, Wh, bh, Wm, bm,
                                                 Wo, bo, out);
}